// Round 5
// baseline (608.313 us; speedup 1.0000x reference)
//
#include <hip/hip_runtime.h>

#define T_TOK 4096
#define H_DIM 1024
#define I_DIM 4096
#define NE 8

typedef _Float16 f16;
typedef _Float16 f16x8 __attribute__((ext_vector_type(8)));
typedef _Float16 f16x4 __attribute__((ext_vector_type(4)));
typedef float f32x4 __attribute__((ext_vector_type(4)));

#define GLOBAL_AS __attribute__((address_space(1)))
#define LDS_AS __attribute__((address_space(3)))

__device__ __forceinline__ void gload_lds16(const void* g, void* l) {
  __builtin_amdgcn_global_load_lds((GLOBAL_AS const unsigned int*)g,
                                   (LDS_AS unsigned int*)l, 16, 0, 0);
}

#define VM4() asm volatile("s_waitcnt vmcnt(4)" ::: "memory")
#define VM3() asm volatile("s_waitcnt vmcnt(3)" ::: "memory")
#define VM0() asm volatile("s_waitcnt vmcnt(0)" ::: "memory")
#define BAR() __builtin_amdgcn_s_barrier()
#define PRIO1() __builtin_amdgcn_s_setprio(1)
#define PRIO0() __builtin_amdgcn_s_setprio(0)

// ---------------------------------------------------------------- cast x -> fp16
__global__ void cast_x_kernel(const float* __restrict__ x, f16* __restrict__ xh) {
  int i = blockIdx.x * 256 + threadIdx.x;
  float4 v = reinterpret_cast<const float4*>(x)[i];
  f16x4 o = {(f16)v.x, (f16)v.y, (f16)v.z, (f16)v.w};
  reinterpret_cast<f16x4*>(xh)[i] = o;
}

// ---------------------------------------------------------------- transpose+cast weights
// z<16: w1/w3 [H][I] -> interleaved w13t [8192][1024]:
//   w1 col c -> row (c>>5)*64 + (c&31);  w3 col c -> row (c>>5)*64 + 32 + (c&31)
// z>=16: w2 [I][H] -> w2t [H][I]
__global__ __launch_bounds__(256) void transpose_cast_kernel(
    const float* __restrict__ w1s, const float* __restrict__ w3s,
    const float* __restrict__ w2s, f16* __restrict__ w13t, f16* __restrict__ w2t) {
  __shared__ float tile[64][65];
  const int z = blockIdx.z;
  const int tr = threadIdx.x >> 4;
  const int tc = (threadIdx.x & 15) * 4;
  if (z < 16) {
    int e = z & 7;
    const float* in = (z < 8 ? w1s : w3s) + (size_t)e * H_DIM * I_DIM;
    f16* out = w13t + (size_t)e * (2 * H_DIM * I_DIM);
    const int roff = (z < 8) ? 0 : 32;
    const int c0 = blockIdx.x * 64, r0 = blockIdx.y * 64;  // c0 in I-space, r0 in H-space
#pragma unroll
    for (int i = 0; i < 4; ++i) {
      int r = tr + i * 16;
      float4 v = *reinterpret_cast<const float4*>(&in[(size_t)(r0 + r) * I_DIM + c0 + tc]);
      tile[r][tc] = v.x; tile[r][tc + 1] = v.y; tile[r][tc + 2] = v.z; tile[r][tc + 3] = v.w;
    }
    __syncthreads();
#pragma unroll
    for (int i = 0; i < 4; ++i) {
      int oc = tr + i * 16;
      int cg = c0 + oc;
      int rowo = ((cg >> 5) << 6) + roff + (cg & 31);
      f16x4 h;
#pragma unroll
      for (int j = 0; j < 4; ++j) h[j] = (f16)tile[tc + j][oc];
      *reinterpret_cast<f16x4*>(&out[(size_t)rowo * H_DIM + r0 + tc]) = h;
    }
  } else {
    int e = z - 16;
    const float* in = w2s + (size_t)e * H_DIM * I_DIM;
    f16* out = w2t + (size_t)e * H_DIM * I_DIM;
    const int r0 = blockIdx.x * 64, c0 = blockIdx.y * 64;  // r0 in I-space, c0 in H-space
#pragma unroll
    for (int i = 0; i < 4; ++i) {
      int r = tr + i * 16;
      float4 v = *reinterpret_cast<const float4*>(&in[(size_t)(r0 + r) * H_DIM + c0 + tc]);
      tile[r][tc] = v.x; tile[r][tc + 1] = v.y; tile[r][tc + 2] = v.z; tile[r][tc + 3] = v.w;
    }
    __syncthreads();
#pragma unroll
    for (int i = 0; i < 4; ++i) {
      int oc = tr + i * 16;
      f16x4 h;
#pragma unroll
      for (int j = 0; j < 4; ++j) h[j] = (f16)tile[tc + j][oc];
      *reinterpret_cast<f16x4*>(&out[(size_t)(c0 + oc) * I_DIM + r0 + tc]) = h;
    }
  }
}

// ---------------------------------------------------------------- router (1 wave / token)
__global__ void router_kernel(const float* __restrict__ x, const float* __restrict__ gw,
                              int* __restrict__ counts, int* __restrict__ lists,
                              float* __restrict__ wgts) {
  const int t = blockIdx.x;
  const int l = threadIdx.x;
  const float* xr = x + (size_t)t * H_DIM;
  float acc[NE];
#pragma unroll
  for (int e = 0; e < NE; ++e) acc[e] = 0.f;
  for (int k = l; k < H_DIM; k += 64) {
    float xv = xr[k];
#pragma unroll
    for (int e = 0; e < NE; ++e) acc[e] += xv * gw[k * NE + e];
  }
#pragma unroll
  for (int e = 0; e < NE; ++e) {
    float v = acc[e];
#pragma unroll
    for (int off = 32; off > 0; off >>= 1) v += __shfl_xor(v, off);
    acc[e] = v;
  }
  if (l == 0) {
    int i1 = 0;
#pragma unroll
    for (int e = 1; e < NE; ++e)
      if (acc[e] > acc[i1]) i1 = e;
    int i2 = (i1 == 0) ? 1 : 0;
#pragma unroll
    for (int e = 0; e < NE; ++e)
      if (e != i1 && acc[e] > acc[i2]) i2 = e;
    float wA = 1.f / (1.f + __expf(acc[i2] - acc[i1]));
    float wB = 1.f - wA;
    int p1 = atomicAdd(&counts[i1], 1);
    lists[i1 * T_TOK + p1] = t;
    wgts[i1 * T_TOK + p1] = wA;
    int p2 = atomicAdd(&counts[i2], 1);
    lists[i2 * T_TOK + p2] = t;
    wgts[i2 * T_TOK + p2] = wB;
  }
}

// ---------------------------------------------------------------- padded prefix offsets
__global__ void prefix_kernel(const int* __restrict__ counts, int* __restrict__ bases) {
  if (threadIdx.x == 0) {
    int s = 0;
#pragma unroll
    for (int e = 0; e < NE; ++e) {
      bases[e] = s;
      s += (counts[e] + 127) & ~127;
    }
  }
}

// ---------------------------------------------------------------- GEMM A
// inter = silu(x@w1)*(x@w3), w13t interleaved. Block 256 tok-rows x 256 w13-rows
// (=128 orig cols, both matrices). 8 waves (2x4), wave 128x64. BK=64, dbuf-2,
// 4-phase counted-vmcnt pipeline (never drains in-loop).
// LDS slot layout (A and B each): f16 idx = (kq*512 + row*2 + pp)*8,
//   kq = g>>1 (g = k-octet 0..7), pp = (g&1) ^ ((row>>2)&1).
__global__ __launch_bounds__(512, 1) void gemm_a_kernel(
    const f16* __restrict__ xh, const f16* __restrict__ w13t,
    const int* __restrict__ counts, const int* __restrict__ bases,
    const int* __restrict__ lists, f16* __restrict__ inter) {
  const int z = blockIdx.z;
  const int cnt = counts[z];
  const int r0 = blockIdx.y * 256;
  if (r0 >= cnt) return;
  const int base = bases[z];
  const int pad = (cnt + 127) & ~127;
  const int c0 = blockIdx.x * 256;
  const int tid = threadIdx.x;
  const int lane = tid & 63;
  const int wid = tid >> 6;
  const int wm = wid >> 2, wn = wid & 3;
  const int lrow = lane & 15, lk = lane >> 4;

  __shared__ __align__(16) f16 lds[2][32768];  // [slot][A 16384 | B 16384] = 64KB/slot

  const int* lst = lists + z * T_TOK;
  const f16* w13 = w13t + (size_t)z * (2 * H_DIM * I_DIM);

  // staging: thread -> (srow = tid>>1, pp = tid&1); round r stages k-quarter kq=r.
  const int srow = tid >> 1;
  const int gb = (tid & 1) ^ ((srow >> 2) & 1);
  const int tok = lst[r0 + srow];  // zeroed past cnt -> token 0 (safe pad)
  const f16* asrc = xh + (size_t)tok * H_DIM + gb * 8;
  const f16* bsrc = w13 + (size_t)(c0 + srow) * H_DIM + gb * 8;

#define STG_A(r, S, K) gload_lds16(asrc + (K) + (r) * 16, &lds[S][((r) * 512 + wid * 64) * 8])
#define STG_B(r, S, K) gload_lds16(bsrc + (K) + (r) * 16, &lds[S][16384 + ((r) * 512 + wid * 64) * 8])

  const f32x4 z4 = {0.f, 0.f, 0.f, 0.f};
  f32x4 acc[8][4];
#pragma unroll
  for (int m = 0; m < 8; ++m)
#pragma unroll
    for (int n = 0; n < 4; ++n) acc[m][n] = z4;

  const int NT = H_DIM / 64;  // 16
  // prologue: all 8 rounds of tile 0; counted wait completes kk0 half, leaves kk1 in flight
  STG_A(0, 0, 0); STG_A(1, 0, 0); STG_B(0, 0, 0); STG_B(1, 0, 0);
  STG_A(2, 0, 0); STG_A(3, 0, 0); STG_B(2, 0, 0); STG_B(3, 0, 0);
  VM4(); BAR();

  int cur = 0;
  for (int t = 0; t < NT; ++t) {
    const f16* SA = lds[cur];
    const f16* SB = lds[cur] + 16384;
    const int nxt = cur ^ 1;
    const int ks = (t + 1 < NT ? t + 1 : NT - 1) * 64;  // final-iter dummy restage keeps counts uniform

#pragma unroll
    for (int kk = 0; kk < 2; ++kk) {
      // phase A-stage: issue A half of tile t+1 (kk0: rounds 0,1; kk1: rounds 2,3)
      if (kk == 0) { STG_A(0, nxt, ks); STG_A(1, nxt, ks); }
      else         { STG_A(2, nxt, ks); STG_A(3, nxt, ks); }
      f16x8 af[8];
#pragma unroll
      for (int m = 0; m < 8; ++m) {
        int row = wm * 128 + m * 16 + lrow;
        int idx = ((kk * 2 + (lk >> 1)) * 512 + row * 2 + ((lk & 1) ^ ((row >> 2) & 1))) * 8;
        af[m] = *reinterpret_cast<const f16x8*>(&SA[idx]);
      }
#pragma unroll
      for (int nh = 0; nh < 2; ++nh) {
        if (nh == 1) {
          if (kk == 0) { STG_B(0, nxt, ks); STG_B(1, nxt, ks); }
          else         { STG_B(2, nxt, ks); STG_B(3, nxt, ks); }
        }
        f16x8 bf[2];
#pragma unroll
        for (int n = 0; n < 2; ++n) {
          int row = wn * 64 + (nh * 2 + n) * 16 + lrow;
          int idx = ((kk * 2 + (lk >> 1)) * 512 + row * 2 + ((lk & 1) ^ ((row >> 2) & 1))) * 8;
          bf[n] = *reinterpret_cast<const f16x8*>(&SB[idx]);
        }
        PRIO1();
#pragma unroll
        for (int m = 0; m < 8; ++m)
#pragma unroll
          for (int n = 0; n < 2; ++n)
            acc[m][nh * 2 + n] =
                __builtin_amdgcn_mfma_f32_16x16x32_f16(af[m], bf[n], acc[m][nh * 2 + n], 0, 0, 0);
        PRIO0();
      }
      // K-half boundary: complete the half needed next; 4 loads stay in flight
      VM4(); BAR();
    }
    cur ^= 1;
  }
  VM0();
#undef STG_A
#undef STG_B

  // epilogue: SwiGLU in-register (n,n+2 pair same orig column), fp16 store
#pragma unroll
  for (int m = 0; m < 8; ++m)
#pragma unroll
    for (int r = 0; r < 4; ++r) {
      int rowl = wm * 128 + m * 16 + lk * 4 + r;
      if (r0 + rowl < pad) {
        size_t grow = base + r0 + rowl;
#pragma unroll
        for (int n = 0; n < 2; ++n) {
          int col = (c0 >> 1) + wn * 32 + n * 16 + lrow;
          float s1 = acc[m][n][r];
          float s3 = acc[m][n + 2][r];
          float sv = s1 / (1.f + __expf(-s1));
          inter[grow * I_DIM + col] = (f16)(sv * s3);
        }
      }
    }
}

// ---------------------------------------------------------------- GEMM B
// out[tok] += wgt * inter@w2t. Block 128 rows x 256 cols, 8 waves (2x4),
// wave 64x64. BK=64, dbuf-2, 4-phase counted-vmcnt (VM3).
__global__ __launch_bounds__(512, 1) void gemm_b_kernel(
    const f16* __restrict__ inter, const f16* __restrict__ w2t,
    const int* __restrict__ counts, const int* __restrict__ bases,
    const int* __restrict__ lists, const float* __restrict__ wgts,
    float* __restrict__ out) {
  const int z = blockIdx.z;
  const int cnt = counts[z];
  const int r0 = blockIdx.y * 128;
  if (r0 >= cnt) return;
  const int base = bases[z];
  const int c0 = blockIdx.x * 256;
  const int tid = threadIdx.x;
  const int lane = tid & 63;
  const int wid = tid >> 6;
  const int wm = wid >> 2, wn = wid & 3;  // wm 0..1 rows, wn 0..3 cols
  const int lrow = lane & 15, lk = lane >> 4;

  __shared__ __align__(16) f16 lds[2][24576];  // [slot][A 8192 | B 16384] = 48KB/slot

  const int* lst = lists + z * T_TOK;
  const float* wgt = wgts + z * T_TOK;
  const f16* w2 = w2t + (size_t)z * I_DIM * H_DIM;

  // A staging: 1024 slots, 2 rounds; slot = r*512+tid -> kqbit=(tid>>8)&1, row=(tid&255)>>1
  const int rowA = (tid & 255) >> 1;
  const int gbA = (tid & 1) ^ ((rowA >> 2) & 1);
  const f16* asrc = inter + (size_t)(base + r0 + rowA) * I_DIM + ((tid >> 8) & 1) * 16 + gbA * 8;
  // B staging: 2048 slots, 4 rounds (kq = r); row = tid>>1
  const int rowB = tid >> 1;
  const int gbB = (tid & 1) ^ ((rowB >> 2) & 1);
  const f16* bsrc = w2 + (size_t)(c0 + rowB) * I_DIM + gbB * 8;

#define STG_A(r, S, K) gload_lds16(asrc + (K) + (r) * 32, &lds[S][((r) * 512 + wid * 64) * 8])
#define STG_B(r, S, K) gload_lds16(bsrc + (K) + (r) * 16, &lds[S][8192 + ((r) * 512 + wid * 64) * 8])

  const f32x4 z4 = {0.f, 0.f, 0.f, 0.f};
  f32x4 acc[4][4];
#pragma unroll
  for (int m = 0; m < 4; ++m)
#pragma unroll
    for (int n = 0; n < 4; ++n) acc[m][n] = z4;

  const int NT = I_DIM / 64;  // 64
  // prologue: issue order [A0,B0,B1 | A1,B2,B3]; VM3 completes kk0 set
  STG_A(0, 0, 0); STG_B(0, 0, 0); STG_B(1, 0, 0);
  STG_A(1, 0, 0); STG_B(2, 0, 0); STG_B(3, 0, 0);
  VM3(); BAR();

  int cur = 0;
  for (int t = 0; t < NT; ++t) {
    const f16* SA = lds[cur];
    const f16* SB = lds[cur] + 8192;
    const int nxt = cur ^ 1;
    const int ks = (t + 1 < NT ? t + 1 : NT - 1) * 64;

#pragma unroll
    for (int kk = 0; kk < 2; ++kk) {
      if (kk == 0) { STG_A(0, nxt, ks); STG_B(0, nxt, ks); }
      else         { STG_A(1, nxt, ks); STG_B(2, nxt, ks); }
      f16x8 af[4];
#pragma unroll
      for (int m = 0; m < 4; ++m) {
        int row = wm * 64 + m * 16 + lrow;
        int idx = ((kk * 2 + (lk >> 1)) * 256 + row * 2 + ((lk & 1) ^ ((row >> 2) & 1))) * 8;
        af[m] = *reinterpret_cast<const f16x8*>(&SA[idx]);
      }
#pragma unroll
      for (int nh = 0; nh < 2; ++nh) {
        if (nh == 1) { if (kk == 0) STG_B(1, nxt, ks); else STG_B(3, nxt, ks); }
        f16x8 bf[2];
#pragma unroll
        for (int n = 0; n < 2; ++n) {
          int row = wn * 64 + (nh * 2 + n) * 16 + lrow;
          int idx = ((kk * 2 + (lk >> 1)) * 512 + row * 2 + ((lk & 1) ^ ((row >> 2) & 1))) * 8;
          bf[n] = *reinterpret_cast<const f16x8*>(&SB[idx]);
        }
        PRIO1();
#pragma unroll
        for (int m = 0; m < 4; ++m)
#pragma unroll
          for (int n = 0; n < 2; ++n)
            acc[m][nh * 2 + n] =
                __builtin_amdgcn_mfma_f32_16x16x32_f16(af[m], bf[n], acc[m][nh * 2 + n], 0, 0, 0);
        PRIO0();
      }
      VM3(); BAR();
    }
    cur ^= 1;
  }
  VM0();
#undef STG_A
#undef STG_B

  // epilogue: ATOMIC accumulate (same token in two experts' lists; 2 commutative
  // fp32 addends on zeroed buffer = deterministic)
#pragma unroll
  for (int m = 0; m < 4; ++m)
#pragma unroll
    for (int r = 0; r < 4; ++r) {
      int ri = r0 + wm * 64 + m * 16 + lk * 4 + r;
      if (ri < cnt) {
        int tok = lst[ri];
        float wg = wgt[ri];
        float* orow = out + (size_t)tok * H_DIM + c0 + wn * 64 + lrow;
#pragma unroll
        for (int n = 0; n < 4; ++n) atomicAdd(&orow[n * 16], wg * acc[m][n][r]);
      }
    }
}

// ---------------------------------------------------------------- host
extern "C" void kernel_launch(void* const* d_in, const int* in_sizes, int n_in,
                              void* d_out, int out_size, void* d_ws, size_t ws_size,
                              hipStream_t stream) {
  const float* x = (const float*)d_in[0];
  const float* gw = (const float*)d_in[1];
  const float* w1s = (const float*)d_in[2];
  const float* w2s = (const float*)d_in[3];
  const float* w3s = (const float*)d_in[4];
  float* out = (float*)d_out;

  char* ws = (char*)d_ws;
  f16* xh = (f16*)ws;                                   // 8 MiB
  f16* inter = (f16*)(ws + ((size_t)8 << 20));          // 72 MiB
  f16* w13t = (f16*)(ws + ((size_t)80 << 20));          // 128 MiB (interleaved w1|w3)
  f16* w2t = (f16*)(ws + ((size_t)208 << 20));          // 64 MiB
  char* meta = ws + ((size_t)272 << 20);
  int* counts = (int*)meta;
  int* bases = (int*)(meta + 512);
  int* lists = (int*)(meta + 1024);
  float* wgts = (float*)(meta + 1024 + (size_t)NE * T_TOK * 4);

  hipMemsetAsync(out, 0, (size_t)out_size * sizeof(float), stream);
  hipMemsetAsync(meta, 0, 1024 + (size_t)NE * T_TOK * 8, stream);

  cast_x_kernel<<<dim3((T_TOK * H_DIM) / (4 * 256)), dim3(256), 0, stream>>>(x, xh);
  router_kernel<<<dim3(T_TOK), dim3(64), 0, stream>>>(x, gw, counts, lists, wgts);
  prefix_kernel<<<dim3(1), dim3(64), 0, stream>>>(counts, bases);
  transpose_cast_kernel<<<dim3(64, 16, 24), dim3(256), 0, stream>>>(
      w1s, w3s, w2s, w13t, w2t);
  gemm_a_kernel<<<dim3((2 * I_DIM) / 256, T_TOK / 256, NE), dim3(512), 0, stream>>>(
      xh, w13t, counts, bases, lists, inter);
  gemm_b_kernel<<<dim3(H_DIM / 256, T_TOK / 128, NE), dim3(512), 0, stream>>>(
      inter, w2t, counts, bases, lists, wgts, out);
}

// Round 6
// 566.124 us; speedup vs baseline: 1.0745x; 1.0745x over previous
//
#include <hip/hip_runtime.h>

#define T_TOK 4096
#define H_DIM 1024
#define I_DIM 4096
#define NE 8
#define INTER_ROWS 9216

typedef _Float16 f16;
typedef _Float16 f16x8 __attribute__((ext_vector_type(8)));
typedef _Float16 f16x4 __attribute__((ext_vector_type(4)));
typedef float f32x4 __attribute__((ext_vector_type(4)));

#define GLOBAL_AS __attribute__((address_space(1)))
#define LDS_AS __attribute__((address_space(3)))

__device__ __forceinline__ void gload_lds16(const void* g, void* l) {
  __builtin_amdgcn_global_load_lds((GLOBAL_AS const unsigned int*)g,
                                   (LDS_AS unsigned int*)l, 16, 0, 0);
}

#define VM6() asm volatile("s_waitcnt vmcnt(6)" ::: "memory")
#define VM4() asm volatile("s_waitcnt vmcnt(4)" ::: "memory")
#define VM0() asm volatile("s_waitcnt vmcnt(0)" ::: "memory")
#define BAR() __builtin_amdgcn_s_barrier()
#define PRIO1() __builtin_amdgcn_s_setprio(1)
#define PRIO0() __builtin_amdgcn_s_setprio(0)

// ---------------------------------------------------------------- cast x -> fp16
__global__ void cast_x_kernel(const float* __restrict__ x, f16* __restrict__ xh) {
  int i = blockIdx.x * 256 + threadIdx.x;
  float4 v = reinterpret_cast<const float4*>(x)[i];
  f16x4 o = {(f16)v.x, (f16)v.y, (f16)v.z, (f16)v.w};
  reinterpret_cast<f16x4*>(xh)[i] = o;
}

// ---------------------------------------------------------------- transpose+cast weights
// z<16: w1/w3 [H][I] -> interleaved w13t [8192][1024]:
//   w1 col c -> row (c>>5)*64 + (c&31);  w3 col c -> row (c>>5)*64 + 32 + (c&31)
// z>=16: w2 [I][H] -> w2t [H][I]
__global__ __launch_bounds__(256) void transpose_cast_kernel(
    const float* __restrict__ w1s, const float* __restrict__ w3s,
    const float* __restrict__ w2s, f16* __restrict__ w13t, f16* __restrict__ w2t) {
  __shared__ float tile[64][65];
  const int z = blockIdx.z;
  const int tr = threadIdx.x >> 4;
  const int tc = (threadIdx.x & 15) * 4;
  if (z < 16) {
    int e = z & 7;
    const float* in = (z < 8 ? w1s : w3s) + (size_t)e * H_DIM * I_DIM;
    f16* out = w13t + (size_t)e * (2 * H_DIM * I_DIM);
    const int roff = (z < 8) ? 0 : 32;
    const int c0 = blockIdx.x * 64, r0 = blockIdx.y * 64;
#pragma unroll
    for (int i = 0; i < 4; ++i) {
      int r = tr + i * 16;
      float4 v = *reinterpret_cast<const float4*>(&in[(size_t)(r0 + r) * I_DIM + c0 + tc]);
      tile[r][tc] = v.x; tile[r][tc + 1] = v.y; tile[r][tc + 2] = v.z; tile[r][tc + 3] = v.w;
    }
    __syncthreads();
#pragma unroll
    for (int i = 0; i < 4; ++i) {
      int oc = tr + i * 16;
      int cg = c0 + oc;
      int rowo = ((cg >> 5) << 6) + roff + (cg & 31);
      f16x4 h;
#pragma unroll
      for (int j = 0; j < 4; ++j) h[j] = (f16)tile[tc + j][oc];
      *reinterpret_cast<f16x4*>(&out[(size_t)rowo * H_DIM + r0 + tc]) = h;
    }
  } else {
    int e = z - 16;
    const float* in = w2s + (size_t)e * H_DIM * I_DIM;
    f16* out = w2t + (size_t)e * H_DIM * I_DIM;
    const int r0 = blockIdx.x * 64, c0 = blockIdx.y * 64;
#pragma unroll
    for (int i = 0; i < 4; ++i) {
      int r = tr + i * 16;
      float4 v = *reinterpret_cast<const float4*>(&in[(size_t)(r0 + r) * H_DIM + c0 + tc]);
      tile[r][tc] = v.x; tile[r][tc + 1] = v.y; tile[r][tc + 2] = v.z; tile[r][tc + 3] = v.w;
    }
    __syncthreads();
#pragma unroll
    for (int i = 0; i < 4; ++i) {
      int oc = tr + i * 16;
      f16x4 h;
#pragma unroll
      for (int j = 0; j < 4; ++j) h[j] = (f16)tile[tc + j][oc];
      *reinterpret_cast<f16x4*>(&out[(size_t)(c0 + oc) * I_DIM + r0 + tc]) = h;
    }
  }
}

// ---------------------------------------------------------------- router (1 wave / token)
__global__ void router_kernel(const float* __restrict__ x, const float* __restrict__ gw,
                              int* __restrict__ counts, int* __restrict__ lists,
                              float* __restrict__ wgts) {
  const int t = blockIdx.x;
  const int l = threadIdx.x;
  const float* xr = x + (size_t)t * H_DIM;
  float acc[NE];
#pragma unroll
  for (int e = 0; e < NE; ++e) acc[e] = 0.f;
  for (int k = l; k < H_DIM; k += 64) {
    float xv = xr[k];
#pragma unroll
    for (int e = 0; e < NE; ++e) acc[e] += xv * gw[k * NE + e];
  }
#pragma unroll
  for (int e = 0; e < NE; ++e) {
    float v = acc[e];
#pragma unroll
    for (int off = 32; off > 0; off >>= 1) v += __shfl_xor(v, off);
    acc[e] = v;
  }
  if (l == 0) {
    int i1 = 0;
#pragma unroll
    for (int e = 1; e < NE; ++e)
      if (acc[e] > acc[i1]) i1 = e;
    int i2 = (i1 == 0) ? 1 : 0;
#pragma unroll
    for (int e = 0; e < NE; ++e)
      if (e != i1 && acc[e] > acc[i2]) i2 = e;
    float wA = 1.f / (1.f + __expf(acc[i2] - acc[i1]));
    float wB = 1.f - wA;
    int p1 = atomicAdd(&counts[i1], 1);
    lists[i1 * T_TOK + p1] = t;
    wgts[i1 * T_TOK + p1] = wA;
    int p2 = atomicAdd(&counts[i2], 1);
    lists[i2 * T_TOK + p2] = t;
    wgts[i2 * T_TOK + p2] = wB;
  }
}

// ---------------------------------------------------------------- padded prefix offsets
__global__ void prefix_kernel(const int* __restrict__ counts, int* __restrict__ bases) {
  if (threadIdx.x == 0) {
    int s = 0;
#pragma unroll
    for (int e = 0; e < NE; ++e) {
      bases[e] = s;
      s += (counts[e] + 127) & ~127;
    }
  }
}

// ---------------------------------------------------------------- GEMM A
// inter = silu(x@w1)*(x@w3). Block 256 tok x 256 w13-rows (128 orig cols, both mats),
// BK=32, 512 thr / 8 waves (2m x 4n), wave 128x64. 3-slot LDS ring (32KB/slot),
// staged 2 tiles ahead, counted vmcnt(4) -- never drains in-loop.
// LDS swizzle: physical k-slot = logical ^ ((row>>1)&3)  (2-way banks = free).
__global__ __launch_bounds__(512, 2) void gemm_a_kernel(
    const f16* __restrict__ xh, const f16* __restrict__ w13t,
    const int* __restrict__ counts, const int* __restrict__ bases,
    const int* __restrict__ lists, f16* __restrict__ inter) {
  const int z = blockIdx.z;
  const int cnt = counts[z];
  const int r0 = blockIdx.y * 256;
  if (r0 >= cnt) return;
  const int base = bases[z];
  const int pad = (cnt + 127) & ~127;
  const int c0 = blockIdx.x * 256;  // w13-row offset
  const int tid = threadIdx.x;
  const int lane = tid & 63;
  const int wid = tid >> 6;
  const int wm = wid >> 2, wn = wid & 3;
  const int lrow = lane & 15, lk = lane >> 4;

  __shared__ __align__(16) f16 ring[3][16384];  // [A 8192 | B 8192] f16 = 32KB/slot

  const int* lst = lists + z * T_TOK;
  const f16* w13 = w13t + (size_t)z * (2 * H_DIM * I_DIM);

  // staging sources: 2 A + 2 B loads/thread/tile; inverse-swizzled k-slot
  const f16 *asrc[2], *bsrc[2];
#pragma unroll
  for (int i = 0; i < 2; ++i) {
    int sf = i * 512 + tid;
    int row = sf >> 2;                       // 0..255
    int sl = (sf & 3) ^ ((row >> 1) & 3);    // logical k-octet for this physical slot
    int tok = lst[r0 + row];                 // zeroed past cnt -> token 0 (safe)
    asrc[i] = xh + (size_t)tok * H_DIM + sl * 8;
    bsrc[i] = w13 + (size_t)(c0 + row) * H_DIM + sl * 8;
  }

#define STG(S, K)                                                     \
  do {                                                                \
    _Pragma("unroll") for (int i_ = 0; i_ < 2; ++i_)                  \
      gload_lds16(asrc[i_] + (K), (S) + (i_ * 512 + wid * 64) * 8);   \
    _Pragma("unroll") for (int i_ = 0; i_ < 2; ++i_)                  \
      gload_lds16(bsrc[i_] + (K), (S) + 8192 + (i_ * 512 + wid * 64) * 8); \
  } while (0)

  const f32x4 z4 = {0.f, 0.f, 0.f, 0.f};
  f32x4 acc[8][4];
#pragma unroll
  for (int m = 0; m < 8; ++m)
#pragma unroll
    for (int n = 0; n < 4; ++n) acc[m][n] = z4;

  f16 *s0 = ring[0], *s1 = ring[1], *s2 = ring[2];
  const int NT = H_DIM / 32;  // 32
  STG(s0, 0);
  STG(s1, 32);
  VM4();  // tile-0 loads (oldest 4) done; tile-1's 4 in flight
  BAR();

  for (int t = 0; t < NT; ++t) {
    if (t + 2 < NT) STG(s2, (t + 2) * 32);
    f16x8 af[8], bf[4];
#pragma unroll
    for (int m = 0; m < 8; ++m) {
      int row = wm * 128 + m * 16 + lrow;
      af[m] = *reinterpret_cast<const f16x8*>(&s0[(row * 4 + (lk ^ ((row >> 1) & 3))) * 8]);
    }
#pragma unroll
    for (int n = 0; n < 4; ++n) {
      int row = wn * 64 + n * 16 + lrow;
      bf[n] = *reinterpret_cast<const f16x8*>(&s0[8192 + (row * 4 + (lk ^ ((row >> 1) & 3))) * 8]);
    }
    PRIO1();
#pragma unroll
    for (int m = 0; m < 8; ++m)
#pragma unroll
      for (int n = 0; n < 4; ++n)
        acc[m][n] = __builtin_amdgcn_mfma_f32_16x16x32_f16(af[m], bf[n], acc[m][n], 0, 0, 0);
    PRIO0();
    if (t + 2 < NT) VM4(); else VM0();
    BAR();
    f16* tmp = s0; s0 = s1; s1 = s2; s2 = tmp;
  }
#undef STG

  // epilogue: SwiGLU in-register; w13 interleave: n<2 = w1, n+2 = w3 of same col group
#pragma unroll
  for (int m = 0; m < 8; ++m)
#pragma unroll
    for (int r = 0; r < 4; ++r) {
      int rowl = wm * 128 + m * 16 + lk * 4 + r;
      if (r0 + rowl < pad) {
        size_t grow = base + r0 + rowl;
#pragma unroll
        for (int n = 0; n < 2; ++n) {
          int col = (c0 >> 1) + wn * 32 + n * 16 + lrow;
          float v1 = acc[m][n][r];
          float v3 = acc[m][n + 2][r];
          float sv = v1 / (1.f + __expf(-v1));
          inter[grow * I_DIM + col] = (f16)(sv * v3);
        }
      }
    }
}

// ---------------------------------------------------------------- GEMM B
// out[tok] += wgt * inter@w2t. Block 256 rows x 128 cols, split-K x2 (K=2048 each),
// BK=32, 256 thr / 4 waves (2m x 2n), wave 128x64. 3-slot ring 24KB/slot = 72KB
// -> 2 blocks/CU. Counted vmcnt(6).
__global__ __launch_bounds__(256, 2) void gemm_b_kernel(
    const f16* __restrict__ inter, const f16* __restrict__ w2t,
    const int* __restrict__ counts, const int* __restrict__ bases,
    const int* __restrict__ lists, const float* __restrict__ wgts,
    float* __restrict__ out) {
  const int z = blockIdx.z;
  const int cnt = counts[z];
  const int rb = blockIdx.y >> 1, kb = blockIdx.y & 1;
  const int r0 = rb * 256;
  if (r0 >= cnt) return;
  const int base = bases[z];
  const int c0 = blockIdx.x * 128;
  const int tid = threadIdx.x;
  const int lane = tid & 63;
  const int wid = tid >> 6;
  const int wm = wid >> 1, wn = wid & 1;
  const int lrow = lane & 15, lk = lane >> 4;

  __shared__ __align__(16) f16 ring[3][12288];  // [A 8192 | B 4096] f16 = 24KB/slot

  const int* lst = lists + z * T_TOK;
  const float* wgt = wgts + z * T_TOK;
  const f16* w2 = w2t + (size_t)z * I_DIM * H_DIM;
  const int k0 = kb * 2048;

  // A: 4 loads/thread (1024 slots); clamp row to stay inside inter buffer
  const f16* asrc[4];
#pragma unroll
  for (int i = 0; i < 4; ++i) {
    int sf = i * 256 + tid;
    int row = sf >> 2;
    int sl = (sf & 3) ^ ((row >> 1) & 3);
    int gr = base + r0 + row;
    if (gr > INTER_ROWS - 1) gr = INTER_ROWS - 1;  // tail clamp (values discarded)
    asrc[i] = inter + (size_t)gr * I_DIM + k0 + sl * 8;
  }
  // B: 2 loads/thread (512 slots)
  const f16* bsrc[2];
#pragma unroll
  for (int i = 0; i < 2; ++i) {
    int sf = i * 256 + tid;
    int row = sf >> 2;  // 0..127
    int sl = (sf & 3) ^ ((row >> 1) & 3);
    bsrc[i] = w2 + (size_t)(c0 + row) * I_DIM + k0 + sl * 8;
  }

#define STG(S, K)                                                     \
  do {                                                                \
    _Pragma("unroll") for (int i_ = 0; i_ < 4; ++i_)                  \
      gload_lds16(asrc[i_] + (K), (S) + (i_ * 256 + wid * 64) * 8);   \
    _Pragma("unroll") for (int i_ = 0; i_ < 2; ++i_)                  \
      gload_lds16(bsrc[i_] + (K), (S) + 8192 + (i_ * 256 + wid * 64) * 8); \
  } while (0)

  const f32x4 z4 = {0.f, 0.f, 0.f, 0.f};
  f32x4 acc[8][4];
#pragma unroll
  for (int m = 0; m < 8; ++m)
#pragma unroll
    for (int n = 0; n < 4; ++n) acc[m][n] = z4;

  f16 *s0 = ring[0], *s1 = ring[1], *s2 = ring[2];
  const int NT = 2048 / 32;  // 64
  STG(s0, 0);
  STG(s1, 32);
  VM6();
  BAR();

  for (int t = 0; t < NT; ++t) {
    if (t + 2 < NT) STG(s2, (t + 2) * 32);
    f16x8 af[8], bf[4];
#pragma unroll
    for (int m = 0; m < 8; ++m) {
      int row = wm * 128 + m * 16 + lrow;
      af[m] = *reinterpret_cast<const f16x8*>(&s0[(row * 4 + (lk ^ ((row >> 1) & 3))) * 8]);
    }
#pragma unroll
    for (int n = 0; n < 4; ++n) {
      int row = wn * 64 + n * 16 + lrow;
      bf[n] = *reinterpret_cast<const f16x8*>(&s0[8192 + (row * 4 + (lk ^ ((row >> 1) & 3))) * 8]);
    }
    PRIO1();
#pragma unroll
    for (int m = 0; m < 8; ++m)
#pragma unroll
      for (int n = 0; n < 4; ++n)
        acc[m][n] = __builtin_amdgcn_mfma_f32_16x16x32_f16(af[m], bf[n], acc[m][n], 0, 0, 0);
    PRIO0();
    if (t + 2 < NT) VM6(); else VM0();
    BAR();
    f16* tmp = s0; s0 = s1; s1 = s2; s2 = tmp;
  }
#undef STG

  // epilogue: ATOMIC accumulate (token in two experts' lists + split-K x2;
  // commutative fp32 adds on zeroed buffer)
#pragma unroll
  for (int m = 0; m < 8; ++m)
#pragma unroll
    for (int r = 0; r < 4; ++r) {
      int ri = r0 + wm * 128 + m * 16 + lk * 4 + r;
      if (ri < cnt) {
        int tok = lst[ri];
        float wg = wgt[ri];
        float* orow = out + (size_t)tok * H_DIM + c0 + wn * 64 + lrow;
#pragma unroll
        for (int n = 0; n < 4; ++n) atomicAdd(&orow[n * 16], wg * acc[m][n][r]);
      }
    }
}

// ---------------------------------------------------------------- host
extern "C" void kernel_launch(void* const* d_in, const int* in_sizes, int n_in,
                              void* d_out, int out_size, void* d_ws, size_t ws_size,
                              hipStream_t stream) {
  const float* x = (const float*)d_in[0];
  const float* gw = (const float*)d_in[1];
  const float* w1s = (const float*)d_in[2];
  const float* w2s = (const float*)d_in[3];
  const float* w3s = (const float*)d_in[4];
  float* out = (float*)d_out;

  char* ws = (char*)d_ws;
  f16* xh = (f16*)ws;                                   // 8 MiB
  f16* inter = (f16*)(ws + ((size_t)8 << 20));          // 72 MiB (9216 rows)
  f16* w13t = (f16*)(ws + ((size_t)80 << 20));          // 128 MiB (interleaved w1|w3)
  f16* w2t = (f16*)(ws + ((size_t)208 << 20));          // 64 MiB
  char* meta = ws + ((size_t)272 << 20);
  int* counts = (int*)meta;
  int* bases = (int*)(meta + 512);
  int* lists = (int*)(meta + 1024);
  float* wgts = (float*)(meta + 1024 + (size_t)NE * T_TOK * 4);

  hipMemsetAsync(out, 0, (size_t)out_size * sizeof(float), stream);
  hipMemsetAsync(meta, 0, 1024 + (size_t)NE * T_TOK * 8, stream);

  cast_x_kernel<<<dim3((T_TOK * H_DIM) / (4 * 256)), dim3(256), 0, stream>>>(x, xh);
  router_kernel<<<dim3(T_TOK), dim3(64), 0, stream>>>(x, gw, counts, lists, wgts);
  prefix_kernel<<<dim3(1), dim3(64), 0, stream>>>(counts, bases);
  transpose_cast_kernel<<<dim3(64, 16, 24), dim3(256), 0, stream>>>(
      w1s, w3s, w2s, w13t, w2t);
  // grid order: x fastest -> same x lands on same XCD (%8) -> B-panel stays in its L2
  gemm_a_kernel<<<dim3((2 * I_DIM) / 256, T_TOK / 256, NE), dim3(512), 0, stream>>>(
      xh, w13t, counts, bases, lists, inter);
  gemm_b_kernel<<<dim3(H_DIM / 128, 2 * (T_TOK / 256), NE), dim3(256), 0, stream>>>(
      inter, w2t, counts, bases, lists, wgts, out);
}

// Round 7
// 549.090 us; speedup vs baseline: 1.1079x; 1.0310x over previous
//
#include <hip/hip_runtime.h>

#define T_TOK 4096
#define H_DIM 1024
#define I_DIM 4096
#define NE 8
#define INTER_ROWS 9216

typedef _Float16 f16;
typedef _Float16 f16x8 __attribute__((ext_vector_type(8)));
typedef _Float16 f16x4 __attribute__((ext_vector_type(4)));
typedef float f32x4 __attribute__((ext_vector_type(4)));

#define GLOBAL_AS __attribute__((address_space(1)))
#define LDS_AS __attribute__((address_space(3)))

__device__ __forceinline__ void gload_lds16(const void* g, void* l) {
  __builtin_amdgcn_global_load_lds((GLOBAL_AS const unsigned int*)g,
                                   (LDS_AS unsigned int*)l, 16, 0, 0);
}

#define VM0() asm volatile("s_waitcnt vmcnt(0)" ::: "memory")
#define BARF()                          \
  do {                                  \
    asm volatile("" ::: "memory");      \
    __builtin_amdgcn_s_barrier();       \
    asm volatile("" ::: "memory");      \
  } while (0)
#define PRIO1() __builtin_amdgcn_s_setprio(1)
#define PRIO0() __builtin_amdgcn_s_setprio(0)

// ---------------------------------------------------------------- cast x -> fp16
__global__ void cast_x_kernel(const float* __restrict__ x, f16* __restrict__ xh) {
  int i = blockIdx.x * 256 + threadIdx.x;
  float4 v = reinterpret_cast<const float4*>(x)[i];
  f16x4 o = {(f16)v.x, (f16)v.y, (f16)v.z, (f16)v.w};
  reinterpret_cast<f16x4*>(xh)[i] = o;
}

// ---------------------------------------------------------------- transpose+cast weights
// z<16: w1/w3 [H][I] -> interleaved w13t [8192][1024]:
//   w1 col c -> row (c>>5)*64 + (c&31);  w3 col c -> row (c>>5)*64 + 32 + (c&31)
// z>=16: w2 [I][H] -> w2t [H][I]
__global__ __launch_bounds__(256) void transpose_cast_kernel(
    const float* __restrict__ w1s, const float* __restrict__ w3s,
    const float* __restrict__ w2s, f16* __restrict__ w13t, f16* __restrict__ w2t) {
  __shared__ float tile[64][65];
  const int z = blockIdx.z;
  const int tr = threadIdx.x >> 4;
  const int tc = (threadIdx.x & 15) * 4;
  if (z < 16) {
    int e = z & 7;
    const float* in = (z < 8 ? w1s : w3s) + (size_t)e * H_DIM * I_DIM;
    f16* out = w13t + (size_t)e * (2 * H_DIM * I_DIM);
    const int roff = (z < 8) ? 0 : 32;
    const int c0 = blockIdx.x * 64, r0 = blockIdx.y * 64;
#pragma unroll
    for (int i = 0; i < 4; ++i) {
      int r = tr + i * 16;
      float4 v = *reinterpret_cast<const float4*>(&in[(size_t)(r0 + r) * I_DIM + c0 + tc]);
      tile[r][tc] = v.x; tile[r][tc + 1] = v.y; tile[r][tc + 2] = v.z; tile[r][tc + 3] = v.w;
    }
    __syncthreads();
#pragma unroll
    for (int i = 0; i < 4; ++i) {
      int oc = tr + i * 16;
      int cg = c0 + oc;
      int rowo = ((cg >> 5) << 6) + roff + (cg & 31);
      f16x4 h;
#pragma unroll
      for (int j = 0; j < 4; ++j) h[j] = (f16)tile[tc + j][oc];
      *reinterpret_cast<f16x4*>(&out[(size_t)rowo * H_DIM + r0 + tc]) = h;
    }
  } else {
    int e = z - 16;
    const float* in = w2s + (size_t)e * H_DIM * I_DIM;
    f16* out = w2t + (size_t)e * H_DIM * I_DIM;
    const int r0 = blockIdx.x * 64, c0 = blockIdx.y * 64;
#pragma unroll
    for (int i = 0; i < 4; ++i) {
      int r = tr + i * 16;
      float4 v = *reinterpret_cast<const float4*>(&in[(size_t)(r0 + r) * H_DIM + c0 + tc]);
      tile[r][tc] = v.x; tile[r][tc + 1] = v.y; tile[r][tc + 2] = v.z; tile[r][tc + 3] = v.w;
    }
    __syncthreads();
#pragma unroll
    for (int i = 0; i < 4; ++i) {
      int oc = tr + i * 16;
      f16x4 h;
#pragma unroll
      for (int j = 0; j < 4; ++j) h[j] = (f16)tile[tc + j][oc];
      *reinterpret_cast<f16x4*>(&out[(size_t)(c0 + oc) * I_DIM + r0 + tc]) = h;
    }
  }
}

// ---------------------------------------------------------------- router (1 wave / token)
__global__ void router_kernel(const float* __restrict__ x, const float* __restrict__ gw,
                              int* __restrict__ counts, int* __restrict__ lists,
                              float* __restrict__ wgts) {
  const int t = blockIdx.x;
  const int l = threadIdx.x;
  const float* xr = x + (size_t)t * H_DIM;
  float acc[NE];
#pragma unroll
  for (int e = 0; e < NE; ++e) acc[e] = 0.f;
  for (int k = l; k < H_DIM; k += 64) {
    float xv = xr[k];
#pragma unroll
    for (int e = 0; e < NE; ++e) acc[e] += xv * gw[k * NE + e];
  }
#pragma unroll
  for (int e = 0; e < NE; ++e) {
    float v = acc[e];
#pragma unroll
    for (int off = 32; off > 0; off >>= 1) v += __shfl_xor(v, off);
    acc[e] = v;
  }
  if (l == 0) {
    int i1 = 0;
#pragma unroll
    for (int e = 1; e < NE; ++e)
      if (acc[e] > acc[i1]) i1 = e;
    int i2 = (i1 == 0) ? 1 : 0;
#pragma unroll
    for (int e = 0; e < NE; ++e)
      if (e != i1 && acc[e] > acc[i2]) i2 = e;
    float wA = 1.f / (1.f + __expf(acc[i2] - acc[i1]));
    float wB = 1.f - wA;
    int p1 = atomicAdd(&counts[i1], 1);
    lists[i1 * T_TOK + p1] = t;
    wgts[i1 * T_TOK + p1] = wA;
    int p2 = atomicAdd(&counts[i2], 1);
    lists[i2 * T_TOK + p2] = t;
    wgts[i2 * T_TOK + p2] = wB;
  }
}

// ---------------------------------------------------------------- padded prefix offsets
__global__ void prefix_kernel(const int* __restrict__ counts, int* __restrict__ bases) {
  if (threadIdx.x == 0) {
    int s = 0;
#pragma unroll
    for (int e = 0; e < NE; ++e) {
      bases[e] = s;
      s += (counts[e] + 127) & ~127;
    }
  }
}

// ================================================================ GEMM A
// inter = silu(x@w1)*(x@w3), w13t interleaved. Block 256 tok x 256 w13-rows,
// BK=64, dbuf-2 (128 KiB), 512 thr / 8 waves (2m x 4n), wave 128x64.
// 4 phases per K-tile: {bar, [stage 2 units], ds_read (kh,npair) subtile,
// setprio 16 MFMA}. vmcnt(0) only at ph0 -> waits on loads issued 3-4 phases
// earlier (cheap), never drains fresh loads. LDS swizzle: phys_oct = oct^(row&7).
__global__ __launch_bounds__(512, 1) void gemm_a_kernel(
    const f16* __restrict__ xh, const f16* __restrict__ w13t,
    const int* __restrict__ counts, const int* __restrict__ bases,
    const int* __restrict__ lists, f16* __restrict__ inter) {
  const int z = blockIdx.z;
  const int cnt = counts[z];
  const int r0 = blockIdx.y * 256;
  if (r0 >= cnt) return;
  const int base = bases[z], pad = (cnt + 127) & ~127;
  const int c0 = blockIdx.x * 256;
  const int tid = threadIdx.x, lane = tid & 63, wid = tid >> 6;
  const int wm = wid >> 2, wn = wid & 3, lrow = lane & 15, lk = lane >> 4;

  __shared__ __align__(16) f16 lds[2][32768];  // [A 256x64 | B 256x64] x dbuf = 128 KiB

  const int* lst = lists + z * T_TOK;
  const f16* w13 = w13t + (size_t)z * (2 * H_DIM * I_DIM);

  // staging units: 0=A rows 0-127, 1=B rows 0-127, 2=A rows 128-255, 3=B rows 128-255
  // forced-linear LDS dest (chunk cg), source inverse-swizzled: loct = (cg&7)^(row&7)
  const f16* sp[4][2];
  f16* dp[4][2];
#pragma unroll
  for (int j = 0; j < 2; ++j) {
    int cg = (wid * 2 + j) * 64 + lane;  // 0..1023
    int rih = cg >> 3;                   // 0..127
    int loct = (cg & 7) ^ (rih & 7);     // rows h*128+rih: (row&7)==(rih&7)
    int t0 = lst[r0 + rih], t1 = lst[r0 + 128 + rih];
    sp[0][j] = xh + (size_t)t0 * H_DIM + loct * 8;
    sp[2][j] = xh + (size_t)t1 * H_DIM + loct * 8;
    sp[1][j] = w13 + (size_t)(c0 + rih) * H_DIM + loct * 8;
    sp[3][j] = w13 + (size_t)(c0 + 128 + rih) * H_DIM + loct * 8;
    dp[0][j] = &lds[0][cg * 8];
    dp[2][j] = &lds[0][8192 + cg * 8];
    dp[1][j] = &lds[0][16384 + cg * 8];
    dp[3][j] = &lds[0][24576 + cg * 8];
  }

#define STG(u, S, K)                                        \
  do {                                                      \
    gload_lds16(sp[u][0] + (K), dp[u][0] + (S) * 32768);    \
    gload_lds16(sp[u][1] + (K), dp[u][1] + (S) * 32768);    \
  } while (0)

#define LDA(kh)                                                                        \
  {                                                                                    \
    _Pragma("unroll") for (int m_ = 0; m_ < 8; ++m_) {                                 \
      int row = wm * 128 + m_ * 16 + lrow;                                             \
      af[m_] = *reinterpret_cast<const f16x8*>(                                        \
          &SA[row * 64 + (((kh) * 4 + lk) ^ (row & 7)) * 8]);                          \
    }                                                                                  \
  }
#define LDB(kh, np)                                                                    \
  {                                                                                    \
    _Pragma("unroll") for (int n_ = 0; n_ < 2; ++n_) {                                 \
      int row = wn * 64 + ((np) * 2 + n_) * 16 + lrow;                                 \
      bf[n_] = *reinterpret_cast<const f16x8*>(                                        \
          &SB[row * 64 + (((kh) * 4 + lk) ^ (row & 7)) * 8]);                          \
    }                                                                                  \
  }
#define MF(np)                                                                         \
  {                                                                                    \
    PRIO1();                                                                           \
    _Pragma("unroll") for (int m_ = 0; m_ < 8; ++m_)                                   \
        _Pragma("unroll") for (int n_ = 0; n_ < 2; ++n_)                               \
            acc[m_][(np) * 2 + n_] = __builtin_amdgcn_mfma_f32_16x16x32_f16(           \
                af[m_], bf[n_], acc[m_][(np) * 2 + n_], 0, 0, 0);                      \
    PRIO0();                                                                           \
  }

  const f32x4 z4 = {0.f, 0.f, 0.f, 0.f};
  f32x4 acc[8][4];
#pragma unroll
  for (int m = 0; m < 8; ++m)
#pragma unroll
    for (int n = 0; n < 4; ++n) acc[m][n] = z4;

  const int NT = H_DIM / 64;  // 16
  STG(0, 0, 0); STG(1, 0, 0); STG(2, 0, 0); STG(3, 0, 0);

  for (int t = 0; t < NT; ++t) {
    const f16* SA = lds[t & 1];
    const f16* SB = SA + 16384;
    const int S = (t + 1) & 1;
    const int ks = (t + 1 < NT ? t + 1 : NT - 1) * 64;  // dummy restage last iter
    f16x8 af[8], bf[2];
    // ph0: kh0, n-frags 0,1 -- confirm tile t (loads 3-4 phases old), publish, stage A/B h0
    VM0();
    BARF();
    STG(0, S, ks); STG(1, S, ks);
    LDA(0); LDB(0, 0); MF(0);
    // ph1: kh0, n-frags 2,3 -- stage A/B h1
    BARF();
    STG(2, S, ks); STG(3, S, ks);
    LDB(0, 1); MF(1);
    // ph2: kh1, n-frags 0,1
    BARF();
    LDA(1); LDB(1, 0); MF(0);
    // ph3: kh1, n-frags 2,3
    BARF();
    LDB(1, 1); MF(1);
  }
#undef STG
#undef LDA
#undef LDB
#undef MF

  // epilogue: SwiGLU in-register (frags n / n+2 = w1 / w3 of the same orig cols)
#pragma unroll
  for (int m = 0; m < 8; ++m)
#pragma unroll
    for (int r = 0; r < 4; ++r) {
      int rowl = wm * 128 + m * 16 + lk * 4 + r;
      if (r0 + rowl < pad) {
        size_t grow = base + r0 + rowl;
#pragma unroll
        for (int n = 0; n < 2; ++n) {
          int col = (c0 >> 1) + wn * 32 + n * 16 + lrow;
          float v1 = acc[m][n][r];
          float v3 = acc[m][n + 2][r];
          float sv = v1 / (1.f + __expf(-v1));
          inter[grow * I_DIM + col] = (f16)(sv * v3);
        }
      }
    }
}

// ================================================================ GEMM B
// out[tok] += wgt * inter@w2t. Block 256 rows x 256 cols, split-K x2 (K=2048),
// BK=64, dbuf-2 (128 KiB), 512 thr / 8 waves, wave 128x64. Same 4-phase schedule.
__global__ __launch_bounds__(512, 1) void gemm_b_kernel(
    const f16* __restrict__ inter, const f16* __restrict__ w2t,
    const int* __restrict__ counts, const int* __restrict__ bases,
    const int* __restrict__ lists, const float* __restrict__ wgts,
    float* __restrict__ out) {
  const int z = blockIdx.z;
  const int cnt = counts[z];
  const int rb = blockIdx.y >> 1, kb = blockIdx.y & 1;
  const int r0 = rb * 256;
  if (r0 >= cnt) return;
  const int base = bases[z];
  const int c0 = blockIdx.x * 256;
  const int tid = threadIdx.x, lane = tid & 63, wid = tid >> 6;
  const int wm = wid >> 2, wn = wid & 3, lrow = lane & 15, lk = lane >> 4;

  __shared__ __align__(16) f16 lds[2][32768];

  const int* lst = lists + z * T_TOK;
  const float* wgt = wgts + z * T_TOK;
  const f16* w2 = w2t + (size_t)z * I_DIM * H_DIM;
  const int K0 = kb * 2048;

  const f16* sp[4][2];
  f16* dp[4][2];
#pragma unroll
  for (int j = 0; j < 2; ++j) {
    int cg = (wid * 2 + j) * 64 + lane;
    int rih = cg >> 3;
    int loct = (cg & 7) ^ (rih & 7);
    // A rows may run past this expert's region on ragged tails; values land in
    // allocated ws (w13t) and the products are discarded in the epilogue.
    sp[0][j] = inter + (size_t)(base + r0 + rih) * I_DIM + K0 + loct * 8;
    sp[2][j] = inter + (size_t)(base + r0 + 128 + rih) * I_DIM + K0 + loct * 8;
    sp[1][j] = w2 + (size_t)(c0 + rih) * I_DIM + K0 + loct * 8;
    sp[3][j] = w2 + (size_t)(c0 + 128 + rih) * I_DIM + K0 + loct * 8;
    dp[0][j] = &lds[0][cg * 8];
    dp[2][j] = &lds[0][8192 + cg * 8];
    dp[1][j] = &lds[0][16384 + cg * 8];
    dp[3][j] = &lds[0][24576 + cg * 8];
  }

#define STG(u, S, K)                                        \
  do {                                                      \
    gload_lds16(sp[u][0] + (K), dp[u][0] + (S) * 32768);    \
    gload_lds16(sp[u][1] + (K), dp[u][1] + (S) * 32768);    \
  } while (0)

#define LDA(kh)                                                                        \
  {                                                                                    \
    _Pragma("unroll") for (int m_ = 0; m_ < 8; ++m_) {                                 \
      int row = wm * 128 + m_ * 16 + lrow;                                             \
      af[m_] = *reinterpret_cast<const f16x8*>(                                        \
          &SA[row * 64 + (((kh) * 4 + lk) ^ (row & 7)) * 8]);                          \
    }                                                                                  \
  }
#define LDB(kh, np)                                                                    \
  {                                                                                    \
    _Pragma("unroll") for (int n_ = 0; n_ < 2; ++n_) {                                 \
      int row = wn * 64 + ((np) * 2 + n_) * 16 + lrow;                                 \
      bf[n_] = *reinterpret_cast<const f16x8*>(                                        \
          &SB[row * 64 + (((kh) * 4 + lk) ^ (row & 7)) * 8]);                          \
    }                                                                                  \
  }
#define MF(np)                                                                         \
  {                                                                                    \
    PRIO1();                                                                           \
    _Pragma("unroll") for (int m_ = 0; m_ < 8; ++m_)                                   \
        _Pragma("unroll") for (int n_ = 0; n_ < 2; ++n_)                               \
            acc[m_][(np) * 2 + n_] = __builtin_amdgcn_mfma_f32_16x16x32_f16(           \
                af[m_], bf[n_], acc[m_][(np) * 2 + n_], 0, 0, 0);                      \
    PRIO0();                                                                           \
  }

  const f32x4 z4 = {0.f, 0.f, 0.f, 0.f};
  f32x4 acc[8][4];
#pragma unroll
  for (int m = 0; m < 8; ++m)
#pragma unroll
    for (int n = 0; n < 4; ++n) acc[m][n] = z4;

  const int NT = 2048 / 64;  // 32
  STG(0, 0, 0); STG(1, 0, 0); STG(2, 0, 0); STG(3, 0, 0);

  for (int t = 0; t < NT; ++t) {
    const f16* SA = lds[t & 1];
    const f16* SB = SA + 16384;
    const int S = (t + 1) & 1;
    const int ks = (t + 1 < NT ? t + 1 : NT - 1) * 64;
    f16x8 af[8], bf[2];
    VM0();
    BARF();
    STG(0, S, ks); STG(1, S, ks);
    LDA(0); LDB(0, 0); MF(0);
    BARF();
    STG(2, S, ks); STG(3, S, ks);
    LDB(0, 1); MF(1);
    BARF();
    LDA(1); LDB(1, 0); MF(0);
    BARF();
    LDB(1, 1); MF(1);
  }
#undef STG
#undef LDA
#undef LDB
#undef MF

  // epilogue: ATOMIC accumulate (token appears in 2 experts' lists + split-K x2;
  // commutative fp32 adds on a zeroed buffer)
#pragma unroll
  for (int m = 0; m < 8; ++m)
#pragma unroll
    for (int r = 0; r < 4; ++r) {
      int ri = r0 + wm * 128 + m * 16 + lk * 4 + r;
      if (ri < cnt) {
        int tok = lst[ri];
        float wg = wgt[ri];
        float* orow = out + (size_t)tok * H_DIM + c0 + wn * 64 + lrow;
#pragma unroll
        for (int n = 0; n < 4; ++n) atomicAdd(&orow[n * 16], wg * acc[m][n][r]);
      }
    }
}

// ---------------------------------------------------------------- host
extern "C" void kernel_launch(void* const* d_in, const int* in_sizes, int n_in,
                              void* d_out, int out_size, void* d_ws, size_t ws_size,
                              hipStream_t stream) {
  const float* x = (const float*)d_in[0];
  const float* gw = (const float*)d_in[1];
  const float* w1s = (const float*)d_in[2];
  const float* w2s = (const float*)d_in[3];
  const float* w3s = (const float*)d_in[4];
  float* out = (float*)d_out;

  char* ws = (char*)d_ws;
  f16* xh = (f16*)ws;                                   // 8 MiB
  f16* inter = (f16*)(ws + ((size_t)8 << 20));          // 72 MiB (9216 rows)
  f16* w13t = (f16*)(ws + ((size_t)80 << 20));          // 128 MiB (interleaved w1|w3)
  f16* w2t = (f16*)(ws + ((size_t)208 << 20));          // 64 MiB
  char* meta = ws + ((size_t)272 << 20);
  int* counts = (int*)meta;
  int* bases = (int*)(meta + 512);
  int* lists = (int*)(meta + 1024);
  float* wgts = (float*)(meta + 1024 + (size_t)NE * T_TOK * 4);

  hipMemsetAsync(out, 0, (size_t)out_size * sizeof(float), stream);
  hipMemsetAsync(meta, 0, 1024 + (size_t)NE * T_TOK * 8, stream);

  cast_x_kernel<<<dim3((T_TOK * H_DIM) / (4 * 256)), dim3(256), 0, stream>>>(x, xh);
  router_kernel<<<dim3(T_TOK), dim3(64), 0, stream>>>(x, gw, counts, lists, wgts);
  prefix_kernel<<<dim3(1), dim3(64), 0, stream>>>(counts, bases);
  transpose_cast_kernel<<<dim3(64, 16, 24), dim3(256), 0, stream>>>(
      w1s, w3s, w2s, w13t, w2t);
  // x-fastest grid: wgid%8 == x%8 -> all blocks sharing a B-panel land on one XCD (L2 reuse)
  gemm_a_kernel<<<dim3((2 * I_DIM) / 256, T_TOK / 256, NE), dim3(512), 0, stream>>>(
      xh, w13t, counts, bases, lists, inter);
  gemm_b_kernel<<<dim3(H_DIM / 256, 2 * (T_TOK / 256), NE), dim3(512), 0, stream>>>(
      inter, w2t, counts, bases, lists, wgts, out);
}